// Round 1
// 1036.171 us; speedup vs baseline: 1.1041x; 1.1041x over previous
//
#include <hip/hip_runtime.h>
#include <hip/hip_bf16.h>

#define N_PTS 32768
#define NB    16
#define NS    64
#define DIMC  256

// ---------------------------------------------------------------------------
// Kernel 1: farthest point sampling. One 512-thread block per batch.
// 64 points per thread. px/py and the running min-dists live ENTIRELY in
// registers (launch_bounds(512,2) -> 256-VGPR budget, no spill; the previous
// version spilled 96 floats/thread to scratch => 2.3 MB WRITE_SIZE).
// pz is parked in LDS (128 KB) and read back as ds_read_b128.
// Exact-order fp32 arithmetic (no FMA contraction) so the argmax matches the
// reference bit-wise. Tie-break: first (smallest) index.
// ---------------------------------------------------------------------------
__global__ __launch_bounds__(512, 2) void fps_kernel(const float* __restrict__ coor,
                                                     int* __restrict__ idx_out) {
  __shared__ float4 s_pz[16 * 512];   // 128 KB: z-coords, 4 pts/thread/group
  __shared__ float  s_rv[8];
  __shared__ int    s_ri[8];
  __shared__ float  s_c[3];
  const int b = blockIdx.x;
  const int t = threadIdx.x;
  const float* __restrict__ C = coor + (size_t)b * N_PTS * 3;

  float px[64], py[64], d[64];
#pragma unroll
  for (int g = 0; g < 16; ++g) {
    const int p0 = g * 2048 + t * 4;          // 4 consecutive points
    const float4 c0 = *(const float4*)(C + (size_t)p0 * 3);      // x0 y0 z0 x1
    const float4 c1 = *(const float4*)(C + (size_t)p0 * 3 + 4);  // y1 z1 x2 y2
    const float4 c2 = *(const float4*)(C + (size_t)p0 * 3 + 8);  // z2 x3 y3 z3
    px[g * 4 + 0] = c0.x; py[g * 4 + 0] = c0.y;
    px[g * 4 + 1] = c0.w; py[g * 4 + 1] = c1.x;
    px[g * 4 + 2] = c1.z; py[g * 4 + 2] = c1.w;
    px[g * 4 + 3] = c2.y; py[g * 4 + 3] = c2.z;
    s_pz[g * 512 + t] = make_float4(c0.z, c1.y, c2.x, c2.w);
    d[g * 4 + 0] = 1e10f; d[g * 4 + 1] = 1e10f;
    d[g * 4 + 2] = 1e10f; d[g * 4 + 3] = 1e10f;
  }
  if (t == 0) {
    idx_out[b * NS] = 0;
    s_c[0] = C[0]; s_c[1] = C[1]; s_c[2] = C[2];
  }
  __syncthreads();

  for (int step = 1; step < NS; ++step) {
    const float cx = s_c[0], cy = s_c[1], cz = s_c[2];
    float bestv = -1.0f;
    int   besti = 0;
#pragma unroll
    for (int g = 0; g < 16; ++g) {
      const float4 pz4 = s_pz[g * 512 + t];
      const int pb = g * 2048 + t * 4;
#pragma unroll
      for (int k = 0; k < 4; ++k) {
        const float pz = (k == 0) ? pz4.x : (k == 1) ? pz4.y : (k == 2) ? pz4.z : pz4.w;
        const float dx = __fsub_rn(px[g * 4 + k], cx);
        const float dy = __fsub_rn(py[g * 4 + k], cy);
        const float dz = __fsub_rn(pz, cz);
        const float dd = __fadd_rn(__fadd_rn(__fmul_rn(dx, dx), __fmul_rn(dy, dy)),
                                   __fmul_rn(dz, dz));
        const float nd = fminf(d[g * 4 + k], dd);
        d[g * 4 + k] = nd;
        if (nd > bestv) { bestv = nd; besti = pb + k; }  // ascending p => first-index ties
      }
    }
    // wave (64-lane) argmax reduce, tie -> smaller index
#pragma unroll
    for (int off = 32; off >= 1; off >>= 1) {
      const float ov = __shfl_down(bestv, off);
      const int   oi = __shfl_down(besti, off);
      if (ov > bestv || (ov == bestv && oi < besti)) { bestv = ov; besti = oi; }
    }
    if ((t & 63) == 0) { s_rv[t >> 6] = bestv; s_ri[t >> 6] = besti; }
    __syncthreads();
    if (t < 64) {  // wave 0: parallel reduce over the 8 per-wave winners
      float v = (t < 8) ? s_rv[t] : -1.0f;
      int   i = (t < 8) ? s_ri[t] : 0x7fffffff;
#pragma unroll
      for (int off = 4; off >= 1; off >>= 1) {
        const float ov = __shfl_down(v, off);
        const int   oi = __shfl_down(i, off);
        if (ov > v || (ov == v && oi < i)) { v = ov; i = oi; }
      }
      if (t == 0) {
        idx_out[b * NS + step] = i;
        s_c[0] = C[i * 3 + 0]; s_c[1] = C[i * 3 + 1]; s_c[2] = C[i * 3 + 2];
      }
    }
    __syncthreads();
  }
}

// ---------------------------------------------------------------------------
// Kernel 2: ball query (first 8 valid indices, early-exit ballot scan) +
// neighborhood means / max + LayerNorms + output 0. One wave per (b,s).
// ---------------------------------------------------------------------------
__global__ __launch_bounds__(64) void neigh_kernel(
    const float* __restrict__ coor, const float* __restrict__ x,
    const float* __restrict__ infeat, const int* __restrict__ idx,
    const float* __restrict__ gq, const float* __restrict__ bq,
    const float* __restrict__ gk, const float* __restrict__ bk,
    float* __restrict__ nq, float* __restrict__ nk, float* __restrict__ stats,
    float* __restrict__ out0) {
  const int bs = blockIdx.x;
  const int b  = bs >> 6;
  const int t  = threadIdx.x;
  const float* __restrict__ C = coor   + (size_t)b * N_PTS * 3;
  const float* __restrict__ X = x      + (size_t)b * N_PTS * DIMC;
  const float* __restrict__ F = infeat + (size_t)b * N_PTS * 3;
  int ci = idx[bs];
  ci = __builtin_amdgcn_readfirstlane(ci);
  const float cx = C[ci * 3 + 0], cy = C[ci * 3 + 1], cz = C[ci * 3 + 2];

  __shared__ int s_nidx[8];
  int found = 0;
  for (int base = 0; base < N_PTS && found < 8; base += 64) {
    const int p = base + t;
    const float dx = __fsub_rn(C[p * 3 + 0], cx);
    const float dy = __fsub_rn(C[p * 3 + 1], cy);
    const float dz = __fsub_rn(C[p * 3 + 2], cz);
    const float d2 = __fadd_rn(__fadd_rn(__fmul_rn(dx, dx), __fmul_rn(dy, dy)),
                               __fmul_rn(dz, dz));
    const bool valid = d2 < 16.0f;
    const unsigned long long m = __ballot(valid);
    if (valid) {
      const int slot = found + (int)__popcll(m & ((1ull << t) - 1ull));
      if (slot < 8) s_nidx[slot] = p;
    }
    found += (int)__popcll(m);
  }
  __syncthreads();
  if (t == 0) {
    const int total = found < 8 ? found : 8;
    for (int k = total; k < 8; ++k) s_nidx[k] = s_nidx[0];  // pad with first
  }
  __syncthreads();

  // neighbor coordinate / feature means (lanes 0..7 hold one neighbor each)
  float ax = 0, ay = 0, az = 0, fx = 0, fy = 0, fz = 0;
  if (t < 8) {
    const int n = s_nidx[t];
    ax = C[n * 3 + 0]; ay = C[n * 3 + 1]; az = C[n * 3 + 2];
    fx = F[n * 3 + 0]; fy = F[n * 3 + 1]; fz = F[n * 3 + 2];
  }
#pragma unroll
  for (int off = 4; off >= 1; off >>= 1) {
    ax += __shfl_down(ax, off); ay += __shfl_down(ay, off); az += __shfl_down(az, off);
    fx += __shfl_down(fx, off); fy += __shfl_down(fy, off); fz += __shfl_down(fz, off);
  }
  if (t == 0) {
    float* dco = stats;
    float* dif = stats + 3072;
    float* sco = stats + 6144;
    float* sif = stats + 9216;
    dco[bs * 3 + 0] = ax * 0.125f - cx;
    dco[bs * 3 + 1] = ay * 0.125f - cy;
    dco[bs * 3 + 2] = az * 0.125f - cz;
    dif[bs * 3 + 0] = fx * 0.125f;
    dif[bs * 3 + 1] = fy * 0.125f;
    dif[bs * 3 + 2] = fz * 0.125f;
    sco[bs * 3 + 0] = cx; sco[bs * 3 + 1] = cy; sco[bs * 3 + 2] = cz;
    sif[bs * 3 + 0] = F[ci * 3 + 0];
    sif[bs * 3 + 1] = F[ci * 3 + 1];
    sif[bs * 3 + 2] = F[ci * 3 + 2];
  }

  // global_x = max over 8 neighbor rows; out0 = global_x; LN(x2)->nq, LN(sx)->nk
  const int c0 = t * 4;
  int nn[8];
#pragma unroll
  for (int k = 0; k < 8; ++k) nn[k] = s_nidx[k];
  float4 g = *(const float4*)(X + (size_t)nn[0] * DIMC + c0);
#pragma unroll
  for (int k = 1; k < 8; ++k) {
    const float4 rr = *(const float4*)(X + (size_t)nn[k] * DIMC + c0);
    g.x = fmaxf(g.x, rr.x); g.y = fmaxf(g.y, rr.y);
    g.z = fmaxf(g.z, rr.z); g.w = fmaxf(g.w, rr.w);
  }
  const float4 sx = *(const float4*)(X + (size_t)ci * DIMC + c0);

  // out0 = sample_x + (global_x - sample_x) = global_x  (fp32 output)
  *(float4*)(out0 + (size_t)bs * DIMC + c0) = g;

  const float4 x2 = make_float4(g.x - sx.x, g.y - sx.y, g.z - sx.z, g.w - sx.w);

  float s1 = x2.x + x2.y + x2.z + x2.w;
  float s2 = x2.x * x2.x + x2.y * x2.y + x2.z * x2.z + x2.w * x2.w;
  float u1 = sx.x + sx.y + sx.z + sx.w;
  float u2 = sx.x * sx.x + sx.y * sx.y + sx.z * sx.z + sx.w * sx.w;
#pragma unroll
  for (int off = 1; off < 64; off <<= 1) {
    s1 += __shfl_xor(s1, off); s2 += __shfl_xor(s2, off);
    u1 += __shfl_xor(u1, off); u2 += __shfl_xor(u2, off);
  }
  const float mq = s1 * (1.0f / 256.0f);
  const float vq = s2 * (1.0f / 256.0f) - mq * mq;
  const float rq = 1.0f / sqrtf(vq + 1e-5f);
  const float mk = u1 * (1.0f / 256.0f);
  const float vk = u2 * (1.0f / 256.0f) - mk * mk;
  const float rk = 1.0f / sqrtf(vk + 1e-5f);

  const float4 gqv = *(const float4*)(gq + c0);
  const float4 bqv = *(const float4*)(bq + c0);
  const float4 gkv = *(const float4*)(gk + c0);
  const float4 bkv = *(const float4*)(bk + c0);

  float4 nqv = make_float4((x2.x - mq) * rq * gqv.x + bqv.x,
                           (x2.y - mq) * rq * gqv.y + bqv.y,
                           (x2.z - mq) * rq * gqv.z + bqv.z,
                           (x2.w - mq) * rq * gqv.w + bqv.w);
  float4 nkv = make_float4((sx.x - mk) * rk * gkv.x + bkv.x,
                           (sx.y - mk) * rk * gkv.y + bkv.y,
                           (sx.z - mk) * rk * gkv.z + bkv.z,
                           (sx.w - mk) * rk * gkv.w + bkv.w);
  *(float4*)(nq + (size_t)bs * DIMC + c0) = nqv;
  *(float4*)(nk + (size_t)bs * DIMC + c0) = nkv;
}

// ---------------------------------------------------------------------------
// Kernel 3: M = Wq^T @ Wk  (256x256). 16 blocks x 256 threads.
// ---------------------------------------------------------------------------
__global__ __launch_bounds__(256) void wqwk_kernel(const float* __restrict__ Wq,
                                                   const float* __restrict__ Wk,
                                                   float* __restrict__ M) {
  const int i0 = blockIdx.x * 16;
  const int j  = threadIdx.x;
  float acc[16];
#pragma unroll
  for (int ii = 0; ii < 16; ++ii) acc[ii] = 0.0f;
  for (int c = 0; c < 256; ++c) {
    const float wk = Wk[c * 256 + j];
#pragma unroll
    for (int ii = 0; ii < 16; ++ii) acc[ii] = fmaf(Wq[c * 256 + i0 + ii], wk, acc[ii]);
  }
#pragma unroll
  for (int ii = 0; ii < 16; ++ii) M[(i0 + ii) * 256 + j] = acc[ii];
}

// ---------------------------------------------------------------------------
// Kernel 4: kt[b][m][i] = sum_j M[i][j]*nk[b][m][j]. nk staged in swizzled LDS
// (bank = (j+r)%32 -> conflict-free for row-varying lanes).
// Grid: 16 batches x 8 i-tiles = 128 blocks x 256 threads.
// ---------------------------------------------------------------------------
__global__ __launch_bounds__(256) void kt_kernel(const float* __restrict__ nk,
                                                 const float* __restrict__ M,
                                                 float* __restrict__ kt) {
  __shared__ float lnk[64 * 256];  // 64 KB, swizzled
  const int b  = blockIdx.x >> 3;
  const int it = blockIdx.x & 7;
  const int t  = threadIdx.x;
  const float* __restrict__ NK = nk + (size_t)b * NS * DIMC;
  for (int r = 0; r < 64; ++r) lnk[r * 256 + ((t + r) & 255)] = NK[r * 256 + t];
  __syncthreads();

  const int rr = t & 63;
  const int ig = t >> 6;
  const int i0 = it * 32 + ig * 8;
  float acc[8];
#pragma unroll
  for (int k = 0; k < 8; ++k) acc[k] = 0.0f;
  for (int j = 0; j < 256; ++j) {
    const float v = lnk[rr * 256 + ((j + rr) & 255)];
#pragma unroll
    for (int k = 0; k < 8; ++k) acc[k] = fmaf(M[(i0 + k) * 256 + j], v, acc[k]);
  }
#pragma unroll
  for (int k = 0; k < 8; ++k) kt[((size_t)b * NS + rr) * DIMC + i0 + k] = acc[k];
}

// ---------------------------------------------------------------------------
// Kernel 5: S = nq . kt^T (64x64 per batch), stable softmax, attn @ v for both
// v_coor and v_if (transpose-reshape gather), add residuals, write fp32 out1/2.
// Grid: 16 batches x 4 row-groups = 64 blocks x 256 threads.
// Thread layout: 16 lanes per row (4 m's each) -> shfl width 16 reductions.
// ---------------------------------------------------------------------------
__global__ __launch_bounds__(256) void attn_kernel(const float* __restrict__ nq,
                                                   const float* __restrict__ ktm,
                                                   const float* __restrict__ stats,
                                                   float* __restrict__ out1,
                                                   float* __restrict__ out2) {
  const int blk = blockIdx.x;
  const int b = blk >> 2, rg = blk & 3, t = threadIdx.x;
  const int rl = t >> 4, r = rg * 16 + rl, m0 = (t & 15) * 4;
  const float4* __restrict__ Q = (const float4*)(nq  + ((size_t)b * NS + r)  * DIMC);
  const float4* __restrict__ K = (const float4*)(ktm + ((size_t)b * NS + m0) * DIMC);
  float a0 = 0, a1 = 0, a2 = 0, a3 = 0;
  for (int j = 0; j < 64; ++j) {
    const float4 q  = Q[j];
    const float4 k0 = K[j];
    const float4 k1 = K[j + 64];
    const float4 k2 = K[j + 128];
    const float4 k3 = K[j + 192];
    a0 += q.x * k0.x + q.y * k0.y + q.z * k0.z + q.w * k0.w;
    a1 += q.x * k1.x + q.y * k1.y + q.z * k1.z + q.w * k1.w;
    a2 += q.x * k2.x + q.y * k2.y + q.z * k2.z + q.w * k2.w;
    a3 += q.x * k3.x + q.y * k3.y + q.z * k3.z + q.w * k3.w;
  }
  float mx = fmaxf(fmaxf(a0, a1), fmaxf(a2, a3));
#pragma unroll
  for (int off = 1; off < 16; off <<= 1) mx = fmaxf(mx, __shfl_xor(mx, off, 16));
  const float e0 = expf(a0 - mx), e1 = expf(a1 - mx), e2 = expf(a2 - mx), e3 = expf(a3 - mx);
  float sm = e0 + e1 + e2 + e3;
#pragma unroll
  for (int off = 1; off < 16; off <<= 1) sm += __shfl_xor(sm, off, 16);
  const float inv = 1.0f / sm;
  float pr[4] = {e0 * inv, e1 * inv, e2 * inv, e3 * inv};

  const float* dco = stats;
  const float* dif = stats + 3072;
  const float* sco = stats + 6144;
  const float* sif = stats + 9216;
#pragma unroll
  for (int c = 0; c < 3; ++c) {
    float oc = 0, oi = 0;
#pragma unroll
    for (int mm = 0; mm < 4; ++mm) {
      const int q3 = 3 * (m0 + mm) + c;     // v[m][c] = diff[(3m+c)%64][(3m+c)/64]
      const int row = q3 & 63, col = q3 >> 6;
      oc = fmaf(pr[mm], dco[((size_t)b * NS + row) * 3 + col], oc);
      oi = fmaf(pr[mm], dif[((size_t)b * NS + row) * 3 + col], oi);
    }
#pragma unroll
    for (int off = 1; off < 16; off <<= 1) {
      oc += __shfl_xor(oc, off, 16);
      oi += __shfl_xor(oi, off, 16);
    }
    if ((t & 15) == 0) {
      const size_t o = ((size_t)b * NS + r) * 3 + c;
      out1[o] = sco[o] + oc;
      out2[o] = sif[o] + oi;
    }
  }
}

// ---------------------------------------------------------------------------
extern "C" void kernel_launch(void* const* d_in, const int* in_sizes, int n_in,
                              void* d_out, int out_size, void* d_ws, size_t ws_size,
                              hipStream_t stream) {
  const float* infeat = (const float*)d_in[0];
  const float* x      = (const float*)d_in[1];
  const float* coor   = (const float*)d_in[2];
  const float* Wq     = (const float*)d_in[3];
  const float* Wk     = (const float*)d_in[4];
  const float* gq     = (const float*)d_in[5];
  const float* bq     = (const float*)d_in[6];
  const float* gk     = (const float*)d_in[7];
  const float* bk     = (const float*)d_in[8];

  float* out0 = (float*)d_out;                      // (16,64,256) fp32
  float* out1 = out0 + (size_t)NB * NS * DIMC;      // (16,64,3)   fp32
  float* out2 = out1 + (size_t)NB * NS * 3;         // (16,64,3)   fp32

  char* ws = (char*)d_ws;
  int*   idx   = (int*)(ws);                                   // 4 KB
  float* nq    = (float*)(ws + 4096);                          // 1 MB
  float* nk    = (float*)(ws + 4096 + (1u << 20));             // 1 MB
  float* ktw   = (float*)(ws + 4096 + (2u << 20));             // 1 MB
  float* M     = (float*)(ws + 4096 + (3u << 20));             // 256 KB
  float* stats = (float*)(ws + 4096 + (3u << 20) + (256u << 10)); // 48 KB

  fps_kernel<<<NB, 512, 0, stream>>>(coor, idx);
  wqwk_kernel<<<16, 256, 0, stream>>>(Wq, Wk, M);
  neigh_kernel<<<NB * NS, 64, 0, stream>>>(coor, x, infeat, idx, gq, bq, gk, bk,
                                           nq, nk, stats, out0);
  kt_kernel<<<128, 256, 0, stream>>>(nk, M, ktw);
  attn_kernel<<<64, 256, 0, stream>>>(nq, ktw, stats, out1, out2);
}